// Round 9
// baseline (157.980 us; speedup 1.0000x reference)
//
#include <hip/hip_runtime.h>

// EdgeConv (B=2, N=8192, C=64, K=20, OUT=64):
//  zeroh   -> zero z-histogram
//  proj    -> per-point 64->64 projections (8-way split); by==0 also packs
//             cpack=(x,y,z,|c|^2) and builds the z-bucket histogram
//  prefix  -> exclusive prefix over 1024 z-buckets (off + cursor), per batch
//  scatter -> counting-sort points into z-order: s4g (coords) + sidxg (orig id)
//  knnfeat -> 512 blocks x 1024 thr, 16 waves x 2 queries (8192 waves =
//             8 waves/SIMD; LDS ~20 KB so 2 blocks/CU).  Per query:
//             pass1: lane minima of d~ = |c|^2 - 2 q.c over the 1024
//                    z-nearest (contiguous in sorted order) -> tau via
//                    22-step bisection (any-subset 20-of-64-minima bound)
//             pass2: scan only the certified window |z-zq| <= sqrt(tau+|q|^2)
//                    (contains ALL d~<=tau candidates), ballot-compact
//             fallback: full tight scan if collected > 128 (rare outliers)
//             exact fp64 2-slot rank select (ties -> lower orig idx)
//             feat: edge features + gathered projections + BN/leaky/max

#define NPTS 8192
#define NBATCH 2
#define CH 64
#define KNN 20
#define EDIM 197
#define NBUCK 1024
#define CAPC 128
#define KWAVES 16
#define QW 2
#define QB (KWAVES * QW) // 32 queries per block

__device__ __forceinline__ int zbucket(float z) {
  int b = (int)((z + 4.5f) * (1024.0f / 9.0f));
  return b < 0 ? 0 : (b > 1023 ? 1023 : b);
}

__device__ __forceinline__ float wsum(float v) {
  v += __shfl_xor(v, 1, 64);
  v += __shfl_xor(v, 2, 64);
  v += __shfl_xor(v, 4, 64);
  v += __shfl_xor(v, 8, 64);
  v += __shfl_xor(v, 16, 64);
  v += __shfl_xor(v, 32, 64);
  return v;
}

// monotone-shifted surrogate d~ = |c|^2 - 2 q.c = d^2 - |q|^2 (exact shift);
// identical fmaf chain everywhere -> bitwise-consistent threshold tests
__device__ __forceinline__ float dtilde(float m2x, float m2y, float m2z, float4 c) {
  return fmaf(m2x, c.x, fmaf(m2y, c.y, fmaf(m2z, c.z, c.w)));
}

// exact-enough fp64 distance (fp32 diffs exact in fp64, squares exact)
__device__ __forceinline__ double d2d(float qx, float qy, float qz, float4 c) {
  double dx = (double)qx - (double)c.x;
  double dy = (double)qy - (double)c.y;
  double dz = (double)qz - (double)c.z;
  return dx * dx + dy * dy + dz * dz;
}

__device__ __forceinline__ float bcastf(float v, int l) {
  return __int_as_float(__builtin_amdgcn_readlane(__float_as_int(v), l));
}

__global__ __launch_bounds__(1024) void zeroh_kernel(int* __restrict__ hist) {
  int t = blockIdx.x * 1024 + threadIdx.x;
  if (t < NBATCH * NBUCK) hist[t] = 0;
}

// blockIdx.y in [0,8): mat = by>>2, output-quarter = by&3 (16 channels each).
__global__ __launch_bounds__(256) void proj_kernel(const float* __restrict__ x,
                                                   const float* __restrict__ w,
                                                   float4* __restrict__ cpack,
                                                   float* __restrict__ projc,
                                                   float* __restrict__ projn,
                                                   int* __restrict__ hist) {
  __shared__ float wl[CH * 16];
  int by = blockIdx.y;
  int mat = by >> 2, oq = by & 3;
  for (int i = threadIdx.x; i < CH * 16; i += 256) {
    int c = i >> 4, oo = i & 15;
    int o = oq * 16 + oo;
    float w1 = w[o * EDIM + c];
    float w2 = w[o * EDIM + 64 + c];
    float w3 = w[o * EDIM + 128 + c];
    wl[i] = mat ? (w2 + w3) : (w1 - w2);
  }
  __syncthreads();
  int p = blockIdx.x * 256 + threadIdx.x;
  int b = p >> 13, n = p & (NPTS - 1);
  const float* xb = x + (size_t)b * CH * NPTS + n;
  float acc[16];
#pragma unroll
  for (int o = 0; o < 16; ++o) acc[o] = 0.f;
#pragma unroll 4
  for (int c = 0; c < CH; ++c) {
    float xv = xb[(size_t)c * NPTS];
    const float4* wr = (const float4*)(wl + c * 16);
#pragma unroll
    for (int o4 = 0; o4 < 4; ++o4) {
      float4 wv = wr[o4];
      acc[o4 * 4 + 0] = fmaf(wv.x, xv, acc[o4 * 4 + 0]);
      acc[o4 * 4 + 1] = fmaf(wv.y, xv, acc[o4 * 4 + 1]);
      acc[o4 * 4 + 2] = fmaf(wv.z, xv, acc[o4 * 4 + 2]);
      acc[o4 * 4 + 3] = fmaf(wv.w, xv, acc[o4 * 4 + 3]);
    }
  }
  float* dst = (mat ? projn : projc) + (size_t)p * 64 + oq * 16;
#pragma unroll
  for (int o4 = 0; o4 < 4; ++o4)
    ((float4*)dst)[o4] = make_float4(acc[o4 * 4 + 0], acc[o4 * 4 + 1],
                                     acc[o4 * 4 + 2], acc[o4 * 4 + 3]);
  if (by == 0) {
    float cx = xb[0], cy = xb[(size_t)NPTS], cz = xb[(size_t)2 * NPTS];
    cpack[p] = make_float4(cx, cy, cz, fmaf(cx, cx, fmaf(cy, cy, cz * cz)));
    atomicAdd(&hist[b * NBUCK + zbucket(cz)], 1);
  }
}

__global__ __launch_bounds__(1024) void prefix_kernel(const int* __restrict__ hist,
                                                      int* __restrict__ off,
                                                      int* __restrict__ cursor) {
  __shared__ int s[NBUCK];
  int tid = threadIdx.x;
  for (int b = 0; b < NBATCH; ++b) {
    s[tid] = hist[b * NBUCK + tid];
    __syncthreads();
    for (int o = 1; o < NBUCK; o <<= 1) {
      int t = (tid >= o) ? s[tid - o] : 0;
      __syncthreads();
      s[tid] += t;
      __syncthreads();
    }
    int excl = tid ? s[tid - 1] : 0;
    off[b * (NBUCK + 1) + tid] = excl;
    cursor[b * NBUCK + tid] = excl;
    if (tid == NBUCK - 1) off[b * (NBUCK + 1) + NBUCK] = s[NBUCK - 1];
    __syncthreads();
  }
}

__global__ __launch_bounds__(256) void scatter_kernel(const float4* __restrict__ cpack,
                                                      int* __restrict__ cursor,
                                                      float4* __restrict__ s4g,
                                                      int* __restrict__ sidxg) {
  int t = blockIdx.x * 256 + threadIdx.x;
  int b = t >> 13, n = t & (NPTS - 1);
  float4 c = cpack[t];
  int slot = atomicAdd(&cursor[b * NBUCK + zbucket(c.z)], 1);
  s4g[b * NPTS + slot] = c;
  sidxg[b * NPTS + slot] = n;
}

__global__ __launch_bounds__(1024, 8) void knnfeat_kernel(const float4* __restrict__ cpack,
                                                          const float4* __restrict__ s4g,
                                                          const int* __restrict__ sidxg,
                                                          const int* __restrict__ off,
                                                          const float* __restrict__ projc,
                                                          const float* __restrict__ projn,
                                                          const float* __restrict__ w,
                                                          const float* __restrict__ gamma,
                                                          const float* __restrict__ beta,
                                                          const float* __restrict__ mean,
                                                          const float* __restrict__ var,
                                                          float* __restrict__ out) {
  __shared__ int offL[NBUCK + 1];            // 4.1 KB
  __shared__ unsigned short lidx[KWAVES][CAPC]; // 4 KB (per-wave, one query at a time)
  __shared__ int nselL[KWAVES][KNN];         // 1.25 KB
  __shared__ float zbuf[QB][65];             // 8.3 KB
  int tid = threadIdx.x, lane = tid & 63, wq = tid >> 6;
  int blk = blockIdx.x;              // 512 blocks
  int bb = blk >> 8;
  int n0 = (blk & 255) * QB;
  const float4* sb = s4g + bb * NPTS;
  const int* ib = sidxg + bb * NPTS;
  for (int i = tid; i <= NBUCK; i += 1024) offL[i] = off[bb * (NBUCK + 1) + i];
  __syncthreads();
  unsigned long long lmlt = (1ull << lane) - 1ull;

  // per-lane (=channel) weights/BN constants for the fused feat epilogue
  float wd  = w[lane * EDIM + 192];
  float wld = w[lane * EDIM + 193];
  float wrh = w[lane * EDIM + 194];
  float wdv = w[lane * EDIM + 195];
  float wa  = w[lane * EDIM + 196];
  float sc = gamma[lane] * __builtin_amdgcn_rcpf(__builtin_amdgcn_sqrtf(var[lane] + 1e-5f));
  float muv = mean[lane], bt = beta[lane];

#pragma unroll 1
  for (int qi = 0; qi < QW; ++qi) {
    int gq = bb * NPTS + n0 + wq * QW + qi;
    float4 qp = cpack[gq];
    float m2x = -2.f * qp.x, m2y = -2.f * qp.y, m2z = -2.f * qp.z;
    float q2 = fmaf(qp.x, qp.x, fmaf(qp.y, qp.y, qp.z * qp.z));

    // ---- pass1: lane minima over the 1024 z-nearest (contiguous, sorted)
    int bq = zbucket(qp.z);
    int mid = (offL[bq] + offL[bq + 1]) >> 1;
    int st = mid - 512;
    st = st < 0 ? 0 : (st > NPTS - 1024 ? NPTS - 1024 : st);
    float mm = 3.0e38f;
#pragma unroll 4
    for (int i = 0; i < 16; ++i)
      mm = fminf(mm, dtilde(m2x, m2y, m2z, sb[st + i * 64 + lane]));
    // tau >= d~_(20): bisect; invariant count(mm<=hi)>=20. mm in (-64,64) always.
    float lo = -64.f, hi = 64.f;
#pragma unroll 1
    for (int it = 0; it < 22; ++it) {
      float md = (lo + hi) * 0.5f;
      int c = (int)__popcll(__ballot(mm <= md));
      if (c >= KNN) hi = md; else lo = md;
    }
    float tau = hi;

    // ---- pass2: certified z-window scan; all d~<=tau lie inside it
    float rr = tau + q2; rr = rr < 0.f ? 0.f : rr;
    float r = __builtin_amdgcn_sqrtf(rr) * 1.001f + 1e-4f;
    int e0 = offL[zbucket(qp.z - r)];
    int e1 = offL[zbucket(qp.z + r) + 1];
    int cnt = 0;
    int niter = (e1 - e0 + 63) >> 6;
#pragma unroll 1
    for (int i = 0; i < niter; ++i) {
      int j = e0 + i * 64 + lane;
      int jc = j < NPTS ? j : NPTS - 1;
      bool pr = (j < e1) && (dtilde(m2x, m2y, m2z, sb[jc]) <= tau);
      unsigned long long mk = __ballot(pr);
      if (mk) {
        int ofs = cnt + (int)__popcll(mk & lmlt);
        if (pr && ofs < CAPC) lidx[wq][ofs] = (unsigned short)j;
        cnt += (int)__popcll(mk);
      }
    }
    // ---- rare fallback (loose tau for xy-outliers): full tight scan
    if (cnt > CAPC) {
      mm = 3.0e38f;
#pragma unroll 2
      for (int i = 0; i < NPTS / 64; ++i)
        mm = fminf(mm, dtilde(m2x, m2y, m2z, sb[i * 64 + lane]));
      lo = -64.f; hi = 64.f;
      for (int it = 0; it < 22; ++it) {
        float md = (lo + hi) * 0.5f;
        int c = (int)__popcll(__ballot(mm <= md));
        if (c >= KNN) hi = md; else lo = md;
      }
      tau = hi; cnt = 0;
      for (int i = 0; i < NPTS / 64; ++i) {
        int j = i * 64 + lane;
        bool pr = dtilde(m2x, m2y, m2z, sb[j]) <= tau;
        unsigned long long mk = __ballot(pr);
        if (mk) {
          int ofs = cnt + (int)__popcll(mk & lmlt);
          if (pr && ofs < CAPC) lidx[wq][ofs] = (unsigned short)j;
          cnt += (int)__popcll(mk);
        }
      }
    }
    int C = cnt < CAPC ? cnt : CAPC;

    // ---- exact fp64 rank select (2 slots/lane), ties -> lower ORIGINAL idx
    double d0 = 1e300, d1 = 1e300; int o0 = -1, o1 = -1, s0 = 0, s1 = 0;
    if (lane < C) {
      s0 = lidx[wq][lane];
      d0 = d2d(qp.x, qp.y, qp.z, sb[s0]);
      o0 = ib[s0];
    }
    if (C > 64 && lane + 64 < C) {
      s1 = lidx[wq][lane + 64];
      d1 = d2d(qp.x, qp.y, qp.z, sb[s1]);
      o1 = ib[s1];
    }
    int x0l = __double2loint(d0), x0h = __double2hiint(d0);
    int x1l = __double2loint(d1), x1h = __double2hiint(d1);
    int r0 = 0, r1 = 0;
    int C0 = C < 64 ? C : 64;
#pragma unroll 1
    for (int j = 0; j < C0; ++j) {
      double dj = __hiloint2double(__builtin_amdgcn_readlane(x0h, j),
                                   __builtin_amdgcn_readlane(x0l, j));
      int oj = __builtin_amdgcn_readlane(o0, j);
      r0 += (dj < d0) || (dj == d0 && oj < o0);
      r1 += (dj < d1) || (dj == d1 && oj < o1);
    }
    if (C > 64) {
#pragma unroll 1
      for (int j = 0; j < C - 64; ++j) {
        double dj = __hiloint2double(__builtin_amdgcn_readlane(x1h, j),
                                     __builtin_amdgcn_readlane(x1l, j));
        int oj = __builtin_amdgcn_readlane(o1, j);
        r0 += (dj < d0) || (dj == d0 && oj < o0);
        r1 += (dj < d1) || (dj == d1 && oj < o1);
      }
    }
    if (o0 >= 0 && r0 < KNN) nselL[wq][r0] = o0 | (s0 << 16); // orig | slot
    if (o1 >= 0 && r1 < KNN) nselL[wq][r1] = o1 | (s1 << 16);

    // ---- fused feat + conv + BN/leaky + max-over-k (lane = output channel)
    int pv = nselL[wq][lane < KNN ? lane : 0];
    int js = pv >> 16;
    float4 nb = sb[js];
    float vx = nb.x - qp.x, vy = nb.y - qp.y, vz = nb.z - qp.z;
    float dist = __builtin_amdgcn_sqrtf(fmaf(vx, vx, fmaf(vy, vy, vz * vz)));
    float inv = __builtin_amdgcn_rcpf(dist + 1e-6f);
    float vnx = vx * inv, vny = vy * inv, vnz = vz * inv;
    float msk = (lane < KNN) ? 1.f : 0.f;
    float sd = wsum(dist * msk);
    float szn = wsum(nb.z * msk);
    float sx = wsum(vnx * msk);
    float sy = wsum(vny * msk);
    float s3 = wsum(vnz * msk);
    float ld = sd * (1.f / KNN);
    float rh = qp.z - szn * (1.f / KNN);
    float dev = dist - ld;
    float dvs = wsum(dev * dev * msk);
    float dv = dvs * (1.f / (KNN - 1));
    float mdx = sx * (1.f / KNN), mdy = sy * (1.f / KNN), mdz = s3 * (1.f / KNN);
    float mnorm = __builtin_amdgcn_sqrtf(fmaf(mdx, mdx, fmaf(mdy, mdy, mdz * mdz)));
    float rinv = __builtin_amdgcn_rcpf(mnorm + 1e-6f);
    mdx *= rinv; mdy *= rinv; mdz *= rinv;
    float cosv = vnx * mdx + vny * mdy + vnz * mdz;
    float angle = 1.f - fabsf(cosv);
    float base = projc[(size_t)gq * 64 + lane] + ld * wld + rh * wrh + dv * wdv;
    float zmax = -3.0e38f, zmin = 3.0e38f;
#pragma unroll
    for (int kk = 0; kk < KNN; ++kk) {
      float dk = bcastf(dist, kk);
      float ak = bcastf(angle, kk);
      int jk = __builtin_amdgcn_readlane(pv, kk) & 0xFFFF;
      float z = base + projn[(size_t)(bb * NPTS + jk) * 64 + lane] + dk * wd + ak * wa;
      zmax = fmaxf(zmax, z);
      zmin = fminf(zmin, z);
    }
    float M = (sc >= 0.f) ? zmax : zmin; // BN-scale sign-aware monotone epilogue
    float yv = (M - muv) * sc + bt;
    yv = (yv >= 0.f) ? yv : 0.2f * yv;
    int qcol = wq * QW + qi;
    zbuf[qcol][(lane + qcol) & 63] = yv; // swizzled: conflict-free both ways
  }
  __syncthreads();
  // transpose writeout: out[b][o][n0 .. n0+31]
  if (tid < 512) {
    int g = tid & 7, o = tid >> 3;
    int q4 = g * 4;
    float4 v;
    v.x = zbuf[q4 + 0][(o + q4 + 0) & 63];
    v.y = zbuf[q4 + 1][(o + q4 + 1) & 63];
    v.z = zbuf[q4 + 2][(o + q4 + 2) & 63];
    v.w = zbuf[q4 + 3][(o + q4 + 3) & 63];
    *(float4*)(out + (size_t)bb * CH * NPTS + (size_t)o * NPTS + n0 + q4) = v;
  }
}

extern "C" void kernel_launch(void* const* d_in, const int* in_sizes, int n_in,
                              void* d_out, int out_size, void* d_ws, size_t ws_size,
                              hipStream_t stream) {
  const float* x = (const float*)d_in[0];
  const float* w = (const float*)d_in[1];
  const float* gamma = (const float*)d_in[2];
  const float* beta = (const float*)d_in[3];
  const float* mean = (const float*)d_in[4];
  const float* var = (const float*)d_in[5];
  float* out = (float*)d_out;

  // workspace layout
  const size_t OFF_CPACK = 0;         // 262144
  const size_t OFF_PROJC = 262144;    // 4 MiB
  const size_t OFF_PROJN = 4456448;   // 4 MiB
  const size_t OFF_S4    = 8650752;   // 262144
  const size_t OFF_SIDX  = 8912896;   // 65536
  const size_t OFF_HIST  = 8978432;   // 8192
  const size_t OFF_OFFT  = 8986624;   // 8200
  const size_t OFF_CUR   = 8994824;   // 8192
  const size_t NEED      = 9003016;
  if (ws_size < NEED) return;

  char* ws = (char*)d_ws;
  float4* cpack = (float4*)(ws + OFF_CPACK);
  float* projc = (float*)(ws + OFF_PROJC);
  float* projn = (float*)(ws + OFF_PROJN);
  float4* s4g = (float4*)(ws + OFF_S4);
  int* sidxg = (int*)(ws + OFF_SIDX);
  int* hist = (int*)(ws + OFF_HIST);
  int* offt = (int*)(ws + OFF_OFFT);
  int* cur = (int*)(ws + OFF_CUR);

  zeroh_kernel<<<2, 1024, 0, stream>>>(hist);
  proj_kernel<<<dim3(64, 8), 256, 0, stream>>>(x, w, cpack, projc, projn, hist);
  prefix_kernel<<<1, 1024, 0, stream>>>(hist, offt, cur);
  scatter_kernel<<<64, 256, 0, stream>>>(cpack, cur, s4g, sidxg);
  knnfeat_kernel<<<512, 1024, 0, stream>>>(cpack, s4g, sidxg, offt,
                                           projc, projn, w,
                                           gamma, beta, mean, var, out);
}

// Round 10
// 146.018 us; speedup vs baseline: 1.0819x; 1.0819x over previous
//
#include <hip/hip_runtime.h>

// EdgeConv (B=2, N=8192, C=64, K=20, OUT=64):
//  zeroh   -> zero z-histogram
//  proj    -> per-point 64->64 projections (8-way split); by==0 also packs
//             cpack=(x,y,z,|c|^2) and builds the z-bucket histogram
//  prefix  -> exclusive prefix over 1024 z-buckets (off + cursor), per batch
//  scatter -> counting-sort into z-order: s4g (coords), sidxg (orig id),
//             rinv (orig -> slot)
//  knnfeat -> 256 blocks x 1024 thr, 16 waves x 4 ADJACENT sorted queries.
//             Full sorted tile in LDS (r8's proven scan engine: 1 ds_read_b128
//             feeds 16 VALU). pass1 = 1024-slab around the queries -> tau via
//             24-step bisection (subset bound). pass2 = union certified
//             z-window (~20 iters vs 128). Wave-uniform full-scan fallback if
//             collected > 64. Exact fp64 rank select (ties -> lower orig idx)
//             -> output independent of nondeterministic scatter order.
//             feat epilogue as r8; writes coalesced scratch[sorted_q][o].
//  permute -> scratch[rank[n]][o] -> out[b][o][n] (L2-resident, LDS transpose)

#define NPTS 8192
#define NBATCH 2
#define CH 64
#define KNN 20
#define EDIM 197
#define NBUCK 1024
#define CAPC 64
#define KWAVES 16
#define QW 4
#define QB (KWAVES * QW) // 64 queries per block

__device__ __forceinline__ int zbucket(float z) {
  int b = (int)((z + 4.5f) * (1024.0f / 9.0f));
  return b < 0 ? 0 : (b > 1023 ? 1023 : b);
}

__device__ __forceinline__ float wsum(float v) {
  v += __shfl_xor(v, 1, 64);
  v += __shfl_xor(v, 2, 64);
  v += __shfl_xor(v, 4, 64);
  v += __shfl_xor(v, 8, 64);
  v += __shfl_xor(v, 16, 64);
  v += __shfl_xor(v, 32, 64);
  return v;
}

// monotone-shifted surrogate d~ = |c|^2 - 2 q.c = d^2 - |q|^2 (exact shift);
// identical fmaf chain everywhere -> bitwise-consistent threshold tests
__device__ __forceinline__ float dtilde(float m2x, float m2y, float m2z, float4 c) {
  return fmaf(m2x, c.x, fmaf(m2y, c.y, fmaf(m2z, c.z, c.w)));
}

// exact-enough fp64 distance (fp32 diffs exact in fp64, squares exact)
__device__ __forceinline__ double d2d(float qx, float qy, float qz, float4 c) {
  double dx = (double)qx - (double)c.x;
  double dy = (double)qy - (double)c.y;
  double dz = (double)qz - (double)c.z;
  return dx * dx + dy * dy + dz * dz;
}

__device__ __forceinline__ float bcastf(float v, int l) {
  return __int_as_float(__builtin_amdgcn_readlane(__float_as_int(v), l));
}

__global__ __launch_bounds__(1024) void zeroh_kernel(int* __restrict__ hist) {
  int t = blockIdx.x * 1024 + threadIdx.x;
  if (t < NBATCH * NBUCK) hist[t] = 0;
}

// blockIdx.y in [0,8): mat = by>>2, output-quarter = by&3 (16 channels each).
__global__ __launch_bounds__(256) void proj_kernel(const float* __restrict__ x,
                                                   const float* __restrict__ w,
                                                   float4* __restrict__ cpack,
                                                   float* __restrict__ projc,
                                                   float* __restrict__ projn,
                                                   int* __restrict__ hist) {
  __shared__ float wl[CH * 16];
  int by = blockIdx.y;
  int mat = by >> 2, oq = by & 3;
  for (int i = threadIdx.x; i < CH * 16; i += 256) {
    int c = i >> 4, oo = i & 15;
    int o = oq * 16 + oo;
    float w1 = w[o * EDIM + c];
    float w2 = w[o * EDIM + 64 + c];
    float w3 = w[o * EDIM + 128 + c];
    wl[i] = mat ? (w2 + w3) : (w1 - w2);
  }
  __syncthreads();
  int p = blockIdx.x * 256 + threadIdx.x;
  int b = p >> 13, n = p & (NPTS - 1);
  const float* xb = x + (size_t)b * CH * NPTS + n;
  float acc[16];
#pragma unroll
  for (int o = 0; o < 16; ++o) acc[o] = 0.f;
#pragma unroll 4
  for (int c = 0; c < CH; ++c) {
    float xv = xb[(size_t)c * NPTS];
    const float4* wr = (const float4*)(wl + c * 16);
#pragma unroll
    for (int o4 = 0; o4 < 4; ++o4) {
      float4 wv = wr[o4];
      acc[o4 * 4 + 0] = fmaf(wv.x, xv, acc[o4 * 4 + 0]);
      acc[o4 * 4 + 1] = fmaf(wv.y, xv, acc[o4 * 4 + 1]);
      acc[o4 * 4 + 2] = fmaf(wv.z, xv, acc[o4 * 4 + 2]);
      acc[o4 * 4 + 3] = fmaf(wv.w, xv, acc[o4 * 4 + 3]);
    }
  }
  float* dst = (mat ? projn : projc) + (size_t)p * 64 + oq * 16;
#pragma unroll
  for (int o4 = 0; o4 < 4; ++o4)
    ((float4*)dst)[o4] = make_float4(acc[o4 * 4 + 0], acc[o4 * 4 + 1],
                                     acc[o4 * 4 + 2], acc[o4 * 4 + 3]);
  if (by == 0) {
    float cx = xb[0], cy = xb[(size_t)NPTS], cz = xb[(size_t)2 * NPTS];
    cpack[p] = make_float4(cx, cy, cz, fmaf(cx, cx, fmaf(cy, cy, cz * cz)));
    atomicAdd(&hist[b * NBUCK + zbucket(cz)], 1);
  }
}

__global__ __launch_bounds__(1024) void prefix_kernel(const int* __restrict__ hist,
                                                      int* __restrict__ off,
                                                      int* __restrict__ cursor) {
  __shared__ int s[NBUCK];
  int tid = threadIdx.x;
  for (int b = 0; b < NBATCH; ++b) {
    s[tid] = hist[b * NBUCK + tid];
    __syncthreads();
    for (int o = 1; o < NBUCK; o <<= 1) {
      int t = (tid >= o) ? s[tid - o] : 0;
      __syncthreads();
      s[tid] += t;
      __syncthreads();
    }
    int excl = tid ? s[tid - 1] : 0;
    off[b * (NBUCK + 1) + tid] = excl;
    cursor[b * NBUCK + tid] = excl;
    if (tid == NBUCK - 1) off[b * (NBUCK + 1) + NBUCK] = s[NBUCK - 1];
    __syncthreads();
  }
}

__global__ __launch_bounds__(256) void scatter_kernel(const float4* __restrict__ cpack,
                                                      int* __restrict__ cursor,
                                                      float4* __restrict__ s4g,
                                                      int* __restrict__ sidxg,
                                                      int* __restrict__ rinv) {
  int t = blockIdx.x * 256 + threadIdx.x;
  int b = t >> 13, n = t & (NPTS - 1);
  float4 c = cpack[t];
  int slot = atomicAdd(&cursor[b * NBUCK + zbucket(c.z)], 1);
  s4g[b * NPTS + slot] = c;
  sidxg[b * NPTS + slot] = n;
  rinv[b * NPTS + n] = slot;
}

__global__ __launch_bounds__(1024) void knnfeat_kernel(const float4* __restrict__ s4g,
                                                       const int* __restrict__ sidxg,
                                                       const int* __restrict__ off,
                                                       const float* __restrict__ projc,
                                                       const float* __restrict__ projn,
                                                       const float* __restrict__ w,
                                                       const float* __restrict__ gamma,
                                                       const float* __restrict__ beta,
                                                       const float* __restrict__ mean,
                                                       const float* __restrict__ var,
                                                       float* __restrict__ scratch) {
  __shared__ float4 t4[NPTS];                      // 128 KB sorted tile
  __shared__ int offL[NBUCK + 1];                  // 4.1 KB
  __shared__ unsigned short lidx[KWAVES][QW][CAPC]; // 8 KB
  __shared__ int nsel[KWAVES][QW][KNN];            // 5 KB  (slot | orig<<16)
  int tid = threadIdx.x, lane = tid & 63, wq = tid >> 6;
  int blk = blockIdx.x;            // 256 blocks
  int bb = blk >> 7;
  int q0s = (blk & 127) * QB + wq * QW; // this wave's sorted-query base
  const float4* sb = s4g + bb * NPTS;
  const int* ib = sidxg + bb * NPTS;
  for (int i = tid; i < NPTS; i += 1024) t4[i] = sb[i];
  for (int i = tid; i <= NBUCK; i += 1024) offL[i] = off[bb * (NBUCK + 1) + i];
  unsigned long long lmlt = (1ull << lane) - 1ull;

  float qx[QW], qy[QW], qz[QW], m2x[QW], m2y[QW], m2z[QW], q2[QW];
  int oq[QW];
#pragma unroll
  for (int qi = 0; qi < QW; ++qi) {
    float4 qp = sb[q0s + qi];
    oq[qi] = ib[q0s + qi];
    qx[qi] = qp.x; qy[qi] = qp.y; qz[qi] = qp.z;
    m2x[qi] = -2.f * qp.x; m2y[qi] = -2.f * qp.y; m2z[qi] = -2.f * qp.z;
    q2[qi] = fmaf(qp.x, qp.x, fmaf(qp.y, qp.y, qp.z * qp.z));
  }
  __syncthreads();

  // ---- pass1: lane minima over the 1024-slab around the wave's queries
  int st = q0s + 2 - 512;
  st = st < 0 ? 0 : (st > NPTS - 1024 ? NPTS - 1024 : st);
  float m[QW];
#pragma unroll
  for (int qi = 0; qi < QW; ++qi) m[qi] = 3.0e38f;
#pragma unroll 2
  for (int i = 0; i < 16; ++i) {
    float4 c = t4[st + i * 64 + lane];
#pragma unroll
    for (int qi = 0; qi < QW; ++qi)
      m[qi] = fminf(m[qi], dtilde(m2x[qi], m2y[qi], m2z[qi], c));
  }
  // tau >= d~_(20) (any-subset 20-of-64-lane-minima bound); bisection as r8.
  float lo[QW], hi[QW];
#pragma unroll
  for (int qi = 0; qi < QW; ++qi) { lo[qi] = -256.f; hi[qi] = 256.f; }
#pragma unroll 1
  for (int it = 0; it < 24; ++it) {
#pragma unroll
    for (int qi = 0; qi < QW; ++qi) {
      float mid = (lo[qi] + hi[qi]) * 0.5f;
      int c = (int)__popcll(__ballot(m[qi] <= mid));
      if (c >= KNN) hi[qi] = mid; else lo[qi] = mid;
    }
  }

  // ---- pass2: union certified z-window. Outside q's own window, d~>tau_q
  // provably, so the only predicate needed is d~ <= tau_q.
  int E0 = NPTS, E1 = 0;
#pragma unroll
  for (int qi = 0; qi < QW; ++qi) {
    float rr = hi[qi] + q2[qi]; rr = rr < 0.f ? 0.f : rr;
    float r = sqrtf(rr) * 1.001f + 1e-4f;
    int e0 = offL[zbucket(qz[qi] - r)];
    int e1 = offL[zbucket(qz[qi] + r) + 1];
    E0 = e0 < E0 ? e0 : E0;
    E1 = e1 > E1 ? e1 : E1;
  }
  int cnt[QW];
#pragma unroll
  for (int qi = 0; qi < QW; ++qi) cnt[qi] = 0;
  int niter = (E1 - E0 + 63) >> 6;
#pragma unroll 1
  for (int i = 0; i < niter; ++i) {
    int j = E0 + i * 64 + lane;
    int jc = j < NPTS ? j : NPTS - 1;
    float4 c = t4[jc];
    bool inb = j < E1;
#pragma unroll
    for (int qi = 0; qi < QW; ++qi) {
      bool pr = inb && (dtilde(m2x[qi], m2y[qi], m2z[qi], c) <= hi[qi]);
      unsigned long long mk = __ballot(pr);
      if (mk) {
        int ofs = cnt[qi] + (int)__popcll(mk & lmlt);
        if (pr && ofs < CAPC) lidx[wq][qi][ofs] = (unsigned short)j;
        cnt[qi] += (int)__popcll(mk);
      }
    }
  }
  // ---- rare wave-uniform fallback: full tight scan from LDS (r8 path)
#pragma unroll 1
  for (int qi = 0; qi < QW; ++qi) {
    if (cnt[qi] > CAPC) {
      float mm = 3.0e38f;
#pragma unroll 2
      for (int i = 0; i < NPTS / 64; ++i)
        mm = fminf(mm, dtilde(m2x[qi], m2y[qi], m2z[qi], t4[i * 64 + lane]));
      float flo = -256.f, fhi = 256.f;
      for (int it = 0; it < 24; ++it) {
        float mid = (flo + fhi) * 0.5f;
        int c = (int)__popcll(__ballot(mm <= mid));
        if (c >= KNN) fhi = mid; else flo = mid;
      }
      hi[qi] = fhi; cnt[qi] = 0;
      for (int i = 0; i < NPTS / 64; ++i) {
        int j = i * 64 + lane;
        bool pr = dtilde(m2x[qi], m2y[qi], m2z[qi], t4[j]) <= fhi;
        unsigned long long mk = __ballot(pr);
        if (mk) {
          int ofs = cnt[qi] + (int)__popcll(mk & lmlt);
          if (pr && ofs < CAPC) lidx[wq][qi][ofs] = (unsigned short)j;
          cnt[qi] += (int)__popcll(mk);
        }
      }
    }
  }

  // ---- exact fp64 rank select: ties -> lower ORIGINAL idx (deterministic
  // regardless of scatter order). One candidate per lane (C <= 64).
  double dd[QW]; int ii[QW], ss[QW], cC[QW];
#pragma unroll
  for (int qi = 0; qi < QW; ++qi) {
    cC[qi] = min(cnt[qi], CAPC);
    dd[qi] = 1e300; ii[qi] = -1; ss[qi] = 0;
    if (lane < cC[qi]) {
      int s = lidx[wq][qi][lane];
      dd[qi] = d2d(qx[qi], qy[qi], qz[qi], t4[s]);
      ii[qi] = ib[s];
      ss[qi] = s;
    }
  }
#pragma unroll
  for (int qi = 0; qi < QW; ++qi) {
    int xlo = __double2loint(dd[qi]), xhi = __double2hiint(dd[qi]);
    int r = 0;
#pragma unroll 1
    for (int j = 0; j < cC[qi]; ++j) {
      double dj = __hiloint2double(__builtin_amdgcn_readlane(xhi, j),
                                   __builtin_amdgcn_readlane(xlo, j));
      int idj = __builtin_amdgcn_readlane(ii[qi], j);
      r += (dj < dd[qi]) || (dj == dd[qi] && idj < ii[qi]);
    }
    if (ii[qi] >= 0 && r < KNN) nsel[wq][qi][r] = ss[qi] | (ii[qi] << 16);
  }

  // ---- fused feat + conv + BN/leaky + max-over-k (lane = output channel)
  float wd  = w[lane * EDIM + 192];
  float wld = w[lane * EDIM + 193];
  float wrh = w[lane * EDIM + 194];
  float wdv = w[lane * EDIM + 195];
  float wa  = w[lane * EDIM + 196];
  float sc = gamma[lane] * __builtin_amdgcn_rcpf(__builtin_amdgcn_sqrtf(var[lane] + 1e-5f));
  float muv = mean[lane], bt = beta[lane];
#pragma unroll 2
  for (int qi = 0; qi < QW; ++qi) {
    int pv = nsel[wq][qi][lane < KNN ? lane : 0];
    int js = pv & 0xFFFF;
    float4 nb = t4[js];
    float vx = nb.x - qx[qi], vy = nb.y - qy[qi], vz = nb.z - qz[qi];
    float dist = __builtin_amdgcn_sqrtf(fmaf(vx, vx, fmaf(vy, vy, vz * vz)));
    float inv = __builtin_amdgcn_rcpf(dist + 1e-6f);
    float vnx = vx * inv, vny = vy * inv, vnz = vz * inv;
    float msk = (lane < KNN) ? 1.f : 0.f;
    float sd = wsum(dist * msk);
    float szn = wsum(nb.z * msk);
    float sx = wsum(vnx * msk);
    float sy = wsum(vny * msk);
    float s3 = wsum(vnz * msk);
    float ld = sd * (1.f / KNN);
    float rh = qz[qi] - szn * (1.f / KNN);
    float dev = dist - ld;
    float dvs = wsum(dev * dev * msk);
    float dv = dvs * (1.f / (KNN - 1));
    float mdx = sx * (1.f / KNN), mdy = sy * (1.f / KNN), mdz = s3 * (1.f / KNN);
    float mnorm = __builtin_amdgcn_sqrtf(fmaf(mdx, mdx, fmaf(mdy, mdy, mdz * mdz)));
    float rinv2 = __builtin_amdgcn_rcpf(mnorm + 1e-6f);
    mdx *= rinv2; mdy *= rinv2; mdz *= rinv2;
    float cosv = vnx * mdx + vny * mdy + vnz * mdz;
    float angle = 1.f - fabsf(cosv);
    float base = projc[(size_t)(bb * NPTS + oq[qi]) * 64 + lane]
               + ld * wld + rh * wrh + dv * wdv;
    float zmax = -3.0e38f, zmin = 3.0e38f;
#pragma unroll
    for (int kk = 0; kk < KNN; ++kk) {
      float dk = bcastf(dist, kk);
      float ak = bcastf(angle, kk);
      int jk = __builtin_amdgcn_readlane(pv, kk) >> 16; // orig neighbor id
      float z = base + projn[(size_t)(bb * NPTS + jk) * 64 + lane] + dk * wd + ak * wa;
      zmax = fmaxf(zmax, z);
      zmin = fminf(zmin, z);
    }
    float M = (sc >= 0.f) ? zmax : zmin; // BN-scale sign-aware monotone epilogue
    float yv = (M - muv) * sc + bt;
    yv = (yv >= 0.f) ? yv : 0.2f * yv;
    // coalesced: 64 lanes write one contiguous 256B row per query
    scratch[(size_t)(bb * NPTS + q0s + qi) * 64 + lane] = yv;
  }
}

// scratch[b][slot][o] -> out[b][o][n]  (slot = rinv[n]); L2-resident permute
__global__ __launch_bounds__(256) void permute_kernel(const float* __restrict__ scratch,
                                                      const int* __restrict__ rinv,
                                                      float* __restrict__ out) {
  __shared__ float tile[64][65];
  int tid = threadIdx.x, lane = tid & 63, grp = tid >> 6;
  int blk = blockIdx.x; // 256: bb = blk>>7, n-tile = (blk&127)*64
  int bb = blk >> 7;
  int n0 = (blk & 127) * 64;
  int slot = rinv[bb * NPTS + n0 + lane];
  const float4* row = (const float4*)(scratch + (size_t)(bb * NPTS + slot) * 64);
#pragma unroll
  for (int c4 = 0; c4 < 4; ++c4) {
    float4 v = row[grp * 4 + c4];
    tile[lane][grp * 16 + c4 * 4 + 0] = v.x;
    tile[lane][grp * 16 + c4 * 4 + 1] = v.y;
    tile[lane][grp * 16 + c4 * 4 + 2] = v.z;
    tile[lane][grp * 16 + c4 * 4 + 3] = v.w;
  }
  __syncthreads();
#pragma unroll
  for (int r16 = 0; r16 < 16; ++r16) {
    int o = grp * 16 + r16;
    out[((size_t)bb * CH + o) * NPTS + n0 + lane] = tile[lane][o];
  }
}

extern "C" void kernel_launch(void* const* d_in, const int* in_sizes, int n_in,
                              void* d_out, int out_size, void* d_ws, size_t ws_size,
                              hipStream_t stream) {
  const float* x = (const float*)d_in[0];
  const float* w = (const float*)d_in[1];
  const float* gamma = (const float*)d_in[2];
  const float* beta = (const float*)d_in[3];
  const float* mean = (const float*)d_in[4];
  const float* var = (const float*)d_in[5];
  float* out = (float*)d_out;

  // workspace layout
  const size_t OFF_CPACK = 0;          // 262144
  const size_t OFF_PROJC = 262144;     // 4 MiB
  const size_t OFF_PROJN = 4456448;    // 4 MiB
  const size_t OFF_S4    = 8650752;    // 262144
  const size_t OFF_SIDX  = 8912896;    // 65536
  const size_t OFF_RINV  = 8978432;    // 65536
  const size_t OFF_HIST  = 9043968;    // 8192
  const size_t OFF_OFFT  = 9052160;    // 8200 (+pad)
  const size_t OFF_CUR   = 9060864;    // 8192
  const size_t OFF_SCR   = 9069056;    // 4 MiB
  const size_t NEED      = 9069056 + 4194304;
  if (ws_size < NEED) return;

  char* ws = (char*)d_ws;
  float4* cpack = (float4*)(ws + OFF_CPACK);
  float* projc = (float*)(ws + OFF_PROJC);
  float* projn = (float*)(ws + OFF_PROJN);
  float4* s4g = (float4*)(ws + OFF_S4);
  int* sidxg = (int*)(ws + OFF_SIDX);
  int* rinv = (int*)(ws + OFF_RINV);
  int* hist = (int*)(ws + OFF_HIST);
  int* offt = (int*)(ws + OFF_OFFT);
  int* cur = (int*)(ws + OFF_CUR);
  float* scr = (float*)(ws + OFF_SCR);

  zeroh_kernel<<<2, 1024, 0, stream>>>(hist);
  proj_kernel<<<dim3(64, 8), 256, 0, stream>>>(x, w, cpack, projc, projn, hist);
  prefix_kernel<<<1, 1024, 0, stream>>>(hist, offt, cur);
  scatter_kernel<<<64, 256, 0, stream>>>(cpack, cur, s4g, sidxg, rinv);
  knnfeat_kernel<<<256, 1024, 0, stream>>>(s4g, sidxg, offt, projc, projn, w,
                                           gamma, beta, mean, var, scr);
  permute_kernel<<<256, 256, 0, stream>>>(scr, rinv, out);
}